// Round 4
// baseline (153.857 us; speedup 1.0000x reference)
//
#include <hip/hip_runtime.h>
#include <math.h>

#define ZZ 128
#define CC 12
#define HH 512
#define NB 4096
#define RPB 16            // batch rows per block
#define NBLK (NB / RPB)   // 256 blocks = 1 per CU

typedef __attribute__((ext_vector_type(8))) short short8;
typedef __attribute__((ext_vector_type(4))) float f32x4;

__device__ __forceinline__ unsigned short f2bf(float x) {
    unsigned u = __builtin_bit_cast(unsigned, x);
    u += 0x7FFFu + ((u >> 16) & 1u);
    return (unsigned short)(u >> 16);
}
__device__ __forceinline__ float bf2f(unsigned short h) {
    unsigned u = ((unsigned)h) << 16;
    return __builtin_bit_cast(float, u);
}

// ---------------------------------------------------------------------------
// Prep: W1t/W2t transpose + bf16 hi/lo split ([N][K] layout); edge weights M.
// ---------------------------------------------------------------------------
__global__ __launch_bounds__(256) void k_prep(const float* __restrict__ W1,
                                              const float* __restrict__ W2,
                                              const int* __restrict__ adj,
                                              const int* __restrict__ tt,
                                              const float* __restrict__ w0p,
                                              short* __restrict__ W1tH, short* __restrict__ W1tL,
                                              short* __restrict__ W2tH, short* __restrict__ W2tL,
                                              float* __restrict__ M) {
    int bid = blockIdx.x, t = threadIdx.x;
    if (bid < 80) {
        __shared__ float T[64][65];
        const float* src; short *dH, *dL; int k0, n0, Krows;
        if (bid < 64) { src = W2; dH = W2tH; dL = W2tL; Krows = HH; k0 = (bid & 7) * 64; n0 = (bid >> 3) * 64; }
        else { int b = bid - 64; src = W1; dH = W1tH; dL = W1tL; Krows = ZZ; k0 = (b & 1) * 64; n0 = (b >> 1) * 64; }
#pragma unroll
        for (int it = 0; it < 16; ++it) {
            int idx = t + it * 256; int r = idx >> 6, c = idx & 63;
            T[r][c] = src[(size_t)(k0 + r) * HH + n0 + c];
        }
        __syncthreads();
#pragma unroll
        for (int it = 0; it < 16; ++it) {
            int idx = t + it * 256; int nl = idx >> 6, kl = idx & 63;
            float v = T[kl][nl];
            unsigned short h = f2bf(v);
            float lo = v - bf2f(h);
            size_t o = (size_t)(n0 + nl) * Krows + k0 + kl;
            dH[o] = (short)h; dL[o] = (short)f2bf(lo);
        }
    } else {
        float w0 = w0p[0];
#pragma unroll
        for (int it = 0; it < 64; ++it) {
            int e = t + it * 256;
            M[e] = adj[e] ? expf(-w0 * (float)tt[e]) : 0.f;
        }
    }
}

// ---------------------------------------------------------------------------
// Fused: per block = 16 batch rows. Phase1 stream act/obs -> next_state
// (regs, no cross-thread reduce; thread owns (b_loc, 8 cols)). Phase2 MFMA
// next@W1t. Phase3 MFMA x1@W2t (x1 via LDS, XOR-swizzled). Phase4 Wf dot.
// ---------------------------------------------------------------------------
__global__ __launch_bounds__(256) void k_fused(const float* __restrict__ obs,
                                               const float* __restrict__ act,
                                               const float* __restrict__ M,
                                               const float* __restrict__ w0p,
                                               const short* __restrict__ W1tH,
                                               const short* __restrict__ W1tL,
                                               const short* __restrict__ W2tH,
                                               const short* __restrict__ W2tL,
                                               const float* __restrict__ b1,
                                               const float* __restrict__ b2,
                                               const float* __restrict__ Wf,
                                               const float* __restrict__ bfp,
                                               float* __restrict__ out) {
    __shared__ __align__(16) short AsH[RPB * ZZ], AsL[RPB * ZZ];     // 4+4 KB
    __shared__ __align__(16) short X1H[RPB * HH], X1L[RPB * HH];     // 16+16 KB
    __shared__ float red[4][RPB];

    int t = threadIdx.x;
    int b0 = blockIdx.x * RPB;
    int b_loc = t >> 4, ig = t & 15;            // thread owns (b0+b_loc, cols ig*8..+8)

    // ---------------- Phase 1: next_state ----------------
    const float* ab = act + (size_t)(b0 + b_loc) * ZZ * ZZ + ig * 8;
    const float* mb = M + ig * 8;
    float4 na = make_float4(0.f, 0.f, 0.f, 0.f);
    float4 nb = make_float4(0.f, 0.f, 0.f, 0.f);
#pragma unroll 4
    for (int j = 0; j < ZZ; ++j) {
        float4 a0 = *(const float4*)(ab + (size_t)j * ZZ);
        float4 a1 = *(const float4*)(ab + (size_t)j * ZZ + 4);
        float4 m0 = *(const float4*)(mb + j * ZZ);
        float4 m1 = *(const float4*)(mb + j * ZZ + 4);
        na.x += a0.x * m0.x; na.y += a0.y * m0.y; na.z += a0.z * m0.z; na.w += a0.w * m0.w;
        nb.x += a1.x * m1.x; nb.y += a1.y * m1.y; nb.z += a1.z * m1.z; nb.w += a1.w * m1.w;
    }
    float w[CC];
    {
        float e = expf(-w0p[0]);
        w[0] = 1.f;
#pragma unroll
        for (int c = 1; c < CC; ++c) w[c] = w[c - 1] * e;
    }
    float nx[8] = {na.x, na.y, na.z, na.w, nb.x, nb.y, nb.z, nb.w};
    const float* ob = obs + ((size_t)(b0 + b_loc) * ZZ + ig * 8) * CC;
#pragma unroll
    for (int r = 0; r < 8; ++r) {
        float4 o0 = *(const float4*)(ob + r * CC);
        float4 o1 = *(const float4*)(ob + r * CC + 4);
        float4 o2 = *(const float4*)(ob + r * CC + 8);
        nx[r] += o0.x * w[0] + o0.y * w[1] + o0.z * w[2] + o0.w * w[3]
               + o1.x * w[4] + o1.y * w[5] + o1.z * w[6] + o1.w * w[7]
               + o2.x * w[8] + o2.y * w[9] + o2.z * w[10] + o2.w * w[11];
    }
    // write next_state to d_out
    float* on = out + NB + (size_t)(b0 + b_loc) * ZZ + ig * 8;
    *(float4*)on = make_float4(nx[0], nx[1], nx[2], nx[3]);
    *(float4*)(on + 4) = make_float4(nx[4], nx[5], nx[6], nx[7]);
    // split to LDS (swizzled chunk = ig ^ (row&7))
    {
        int row = b_loc;
        int cs = (ig ^ (row & 7)) << 3;
        short8 hi, lo;
#pragma unroll
        for (int r = 0; r < 8; ++r) {
            unsigned short h = f2bf(nx[r]);
            hi[r] = (short)h;
            lo[r] = (short)f2bf(nx[r] - bf2f(h));
        }
        *(short8*)&AsH[row * ZZ + cs] = hi;
        *(short8*)&AsL[row * ZZ + cs] = lo;
    }
    __syncthreads();

    // ---------------- Phase 2: x1 = relu(next @ W1t^T + b1) ----------------
    int lane = t & 63, wv = t >> 6;
    int l15 = lane & 15, l4 = lane >> 4;
    int nwb = wv * 128;                          // this wave's N-slice [nwb, nwb+128)
    f32x4 acc[8] = {};
    float b1c[8];
#pragma unroll
    for (int nf = 0; nf < 8; ++nf) b1c[nf] = b1[nwb + nf * 16 + l15];
#pragma unroll
    for (int s = 0; s < 4; ++s) {
        int chunk = s * 4 + l4;                  // 0..15 (K=128)
        int aaddr = l15 * ZZ + ((chunk ^ (l15 & 7)) << 3);
        short8 ah = *(const short8*)&AsH[aaddr];
        short8 al = *(const short8*)&AsL[aaddr];
        short8 bh[8], bl[8];
#pragma unroll
        for (int nf = 0; nf < 8; ++nf) {
            int n = nwb + nf * 16 + l15;
            bh[nf] = *(const short8*)&W1tH[(size_t)n * ZZ + chunk * 8];
            bl[nf] = *(const short8*)&W1tL[(size_t)n * ZZ + chunk * 8];
        }
#pragma unroll
        for (int nf = 0; nf < 8; ++nf) {
            acc[nf] = __builtin_amdgcn_mfma_f32_16x16x32_bf16(ah, bh[nf], acc[nf], 0, 0, 0);
            acc[nf] = __builtin_amdgcn_mfma_f32_16x16x32_bf16(ah, bl[nf], acc[nf], 0, 0, 0);
            acc[nf] = __builtin_amdgcn_mfma_f32_16x16x32_bf16(al, bh[nf], acc[nf], 0, 0, 0);
        }
    }
    // epilogue: relu+bias, split, store to X1 LDS (swizzled)
#pragma unroll
    for (int nf = 0; nf < 8; ++nf) {
        int col = nwb + nf * 16 + l15;
        int chunk2 = col >> 3, cw = col & 7;
#pragma unroll
        for (int r = 0; r < 4; ++r) {
            int row = l4 * 4 + r;
            float v = fmaxf(acc[nf][r] + b1c[nf], 0.f);
            unsigned short h = f2bf(v);
            int addr = row * HH + ((chunk2 ^ (row & 7)) << 3) + cw;
            X1H[addr] = (short)h;
            X1L[addr] = (short)f2bf(v - bf2f(h));
        }
    }
    __syncthreads();

    // ---------------- Phase 3: x2 = relu(x1 @ W2t^T + b2) ----------------
    f32x4 acc2[8] = {};
#pragma unroll 2
    for (int ks = 0; ks < 16; ++ks) {
        int chunk = ks * 4 + l4;                 // 0..63 (K=512)
        int aaddr = l15 * HH + ((chunk ^ (l15 & 7)) << 3);
        short8 ah = *(const short8*)&X1H[aaddr];
        short8 al = *(const short8*)&X1L[aaddr];
        short8 bh[8], bl[8];
#pragma unroll
        for (int nf = 0; nf < 8; ++nf) {
            int n = nwb + nf * 16 + l15;
            bh[nf] = *(const short8*)&W2tH[(size_t)n * HH + chunk * 8];
            bl[nf] = *(const short8*)&W2tL[(size_t)n * HH + chunk * 8];
        }
#pragma unroll
        for (int nf = 0; nf < 8; ++nf) {
            acc2[nf] = __builtin_amdgcn_mfma_f32_16x16x32_bf16(ah, bh[nf], acc2[nf], 0, 0, 0);
            acc2[nf] = __builtin_amdgcn_mfma_f32_16x16x32_bf16(ah, bl[nf], acc2[nf], 0, 0, 0);
            acc2[nf] = __builtin_amdgcn_mfma_f32_16x16x32_bf16(al, bh[nf], acc2[nf], 0, 0, 0);
        }
    }

    // ---------------- Phase 4: out[b] = relu(x2)·Wf + bf ----------------
    float b2c[8], wfc[8];
#pragma unroll
    for (int nf = 0; nf < 8; ++nf) {
        int col = nwb + nf * 16 + l15;
        b2c[nf] = b2[col];
        wfc[nf] = Wf[col];
    }
    float p[4];
#pragma unroll
    for (int r = 0; r < 4; ++r) {
        float s = 0.f;
#pragma unroll
        for (int nf = 0; nf < 8; ++nf)
            s += fmaxf(acc2[nf][r] + b2c[nf], 0.f) * wfc[nf];
        s += __shfl_xor(s, 1);
        s += __shfl_xor(s, 2);
        s += __shfl_xor(s, 4);
        s += __shfl_xor(s, 8);
        p[r] = s;
    }
    if (l15 == 0) {
#pragma unroll
        for (int r = 0; r < 4; ++r) red[wv][l4 * 4 + r] = p[r];
    }
    __syncthreads();
    if (t < RPB)
        out[b0 + t] = red[0][t] + red[1][t] + red[2][t] + red[3][t] + bfp[0];
}

extern "C" void kernel_launch(void* const* d_in, const int* in_sizes, int n_in,
                              void* d_out, int out_size, void* d_ws, size_t ws_size,
                              hipStream_t stream) {
    const float* obs = (const float*)d_in[0];
    const float* act = (const float*)d_in[1];
    const float* w0  = (const float*)d_in[2];
    const float* W1  = (const float*)d_in[3];
    const float* b1  = (const float*)d_in[4];
    const float* W2  = (const float*)d_in[5];
    const float* b2  = (const float*)d_in[6];
    const float* Wf  = (const float*)d_in[7];
    const float* bf  = (const float*)d_in[8];
    const int* adj   = (const int*)d_in[9];
    const int* tt    = (const int*)d_in[10];

    float* out = (float*)d_out;               // [0:NB) symbolic_val, [NB:) next_state

    char* base = (char*)d_ws;
    float* M    = (float*)base;                               // 64 KB
    char* p = base + (1u << 16);
    short* W1tH = (short*)p;  p += (size_t)HH * ZZ * 2;       // 128 KB each
    short* W1tL = (short*)p;  p += (size_t)HH * ZZ * 2;
    short* W2tH = (short*)p;  p += (size_t)HH * HH * 2;       // 512 KB each
    short* W2tL = (short*)p;

    k_prep<<<81, 256, 0, stream>>>(W1, W2, adj, tt, w0, W1tH, W1tL, W2tH, W2tL, M);
    k_fused<<<NBLK, 256, 0, stream>>>(obs, act, M, w0, W1tH, W1tL, W2tH, W2tL,
                                      b1, b2, Wf, bf, out);
}